// Round 1
// baseline (1525.974 us; speedup 1.0000x reference)
//
#include <hip/hip_runtime.h>
#include <hip/hip_bf16.h>
#include <stdint.h>

// Problem dims
constexpr int NB = 4;          // batch
constexpr int NF = 16;         // frames
constexpr int NH = 224, NW = 224;
constexpr int HWPIX = NH * NW;             // 50176
constexpr int NPIX = NB * NF * HWPIX;      // 3,211,264
constexpr int OC1 = 64;
constexpr int H1 = 112, W1 = 112;
constexpr int NF2 = 8, H2 = 56, W2 = 56;
constexpr int OC2 = 128;
constexpr int ICC = 32;        // ic chunk for conv2 LDS staging

// ---------------- gray = floor(mean(x, ch) * 255) ----------------
__global__ __launch_bounds__(256) void gray_kernel(const float* __restrict__ x,
                                                   float* __restrict__ gray) {
  int i = blockIdx.x * 256 + threadIdx.x;              // < NPIX
  int b = i / (NF * HWPIX);
  int rem = i - b * (NF * HWPIX);
  const float* xb = x + (size_t)b * 3 * NF * HWPIX + rem;
  float s = xb[0] + xb[NF * HWPIX] + xb[2 * NF * HWPIX];
  gray[i] = floorf((s / 3.0f) * 255.0f);
}

// ---------------- uniform LBP codes + per-block max ----------------
__global__ __launch_bounds__(256) void lbp_kernel(const float* __restrict__ gray,
                                                  float* __restrict__ lbp,
                                                  int* __restrict__ blockmax) {
  int frame = blockIdx.x;                               // 0..63
  int pix = blockIdx.y * 256 + threadIdx.x;             // < 50176
  int y = pix / NW, x = pix - y * NW;
  const float* g = gray + (size_t)frame * HWPIX;

  float n[3][3];
#pragma unroll
  for (int dy = 0; dy < 3; ++dy) {
    int yy = y + dy - 1;
#pragma unroll
    for (int dx = 0; dx < 3; ++dx) {
      int xx = x + dx - 1;
      bool ok = ((unsigned)yy < (unsigned)NH) && ((unsigned)xx < (unsigned)NW);
      n[dy][dx] = ok ? g[yy * NW + xx] : 0.0f;          // cval=0 padding
    }
  }
  float c = n[1][1];

  // skimage offsets rounded to 5 decimals; weights in double then cast (matches
  // python-float scalar * f32 array promotion).
  constexpr double Ad = 0.70711;
  constexpr double Bd = 1.0 - Ad;                        // fr = dr - floor(dr)

  const float s0 = n[1][2];                              // ( 0, +1)
  const float s2 = n[0][1];                              // (-1,  0)
  const float s4 = n[1][0];                              // ( 0, -1)
  const float s6 = n[2][1];                              // (+1,  0)
  // p1: (dr,dc)=(-.70711,.70711) corners (-1,0)(-1,1)(0,0)(0,1)
  const float s1 = (float)(Ad * Bd) * n[0][1] + (float)(Ad * Ad) * n[0][2]
                 + (float)(Bd * Bd) * n[1][1] + (float)(Bd * Ad) * n[1][2];
  // p3: (-.70711,-.70711) corners (-1,-1)(-1,0)(0,-1)(0,0)
  const float s3 = (float)(Ad * Ad) * n[0][0] + (float)(Ad * Bd) * n[0][1]
                 + (float)(Bd * Ad) * n[1][0] + (float)(Bd * Bd) * n[1][1];
  // p5: (.70711,-.70711) corners (0,-1)(0,0)(1,-1)(1,0)
  const float s5 = (float)(Bd * Ad) * n[1][0] + (float)(Bd * Bd) * n[1][1]
                 + (float)(Ad * Ad) * n[2][0] + (float)(Ad * Bd) * n[2][1];
  // p7: (.70711,.70711) corners (0,0)(0,1)(1,0)(1,1)
  const float s7 = (float)(Bd * Bd) * n[1][1] + (float)(Bd * Ad) * n[1][2]
                 + (float)(Ad * Bd) * n[2][1] + (float)(Ad * Ad) * n[2][2];

  bool bb[8] = { s0 >= c, s1 >= c, s2 >= c, s3 >= c,
                 s4 >= c, s5 >= c, s6 >= c, s7 >= c };
  int ones = 0, changes = 0;
#pragma unroll
  for (int p = 0; p < 8; ++p) {
    ones += bb[p] ? 1 : 0;
    changes += (bb[p] != bb[(p + 1) & 7]) ? 1 : 0;
  }
  int code = (changes <= 2) ? ones : 9;
  lbp[(size_t)frame * HWPIX + pix] = (float)code;

  // deterministic block max
  int m = code;
#pragma unroll
  for (int off = 32; off >= 1; off >>= 1) m = max(m, __shfl_down(m, off, 64));
  __shared__ int wm[4];
  if ((threadIdx.x & 63) == 0) wm[threadIdx.x >> 6] = m;
  __syncthreads();
  if (threadIdx.x == 0)
    blockmax[frame * 196 + blockIdx.y] = max(max(wm[0], wm[1]), max(wm[2], wm[3]));
}

__global__ void framemax_kernel(const int* __restrict__ blockmax,
                                int* __restrict__ framemax) {
  int t = threadIdx.x;                                   // 64 threads
  int m = 0;
  for (int j = 0; j < 196; ++j) m = max(m, blockmax[t * 196 + j]);
  framemax[t] = m;
}

__global__ __launch_bounds__(256) void norm_kernel(float* __restrict__ lbp,
                                                   const int* __restrict__ framemax) {
  int i = blockIdx.x * 256 + threadIdx.x;
  int frame = i / HWPIX;
  int m = framemax[frame];
  float v = lbp[i];
  if (m > 0) v = v / (float)m;                           // division, matching ref
  lbp[i] = v;
}

// ---------------- weff[o][k] = sum_c w1[o][c][k] ----------------
__global__ void weff_kernel(const float* __restrict__ w1, float* __restrict__ weff) {
  int o = threadIdx.x;
  if (o < 64) {
    for (int k = 0; k < 27; ++k)
      weff[o * 27 + k] = w1[o * 81 + k] + w1[o * 81 + 27 + k] + w1[o * 81 + 54 + k];
  }
}

// ---------------- conv1: lbp -> h1 (bf16, channel-last [b][f][y][x][ic]) -------
__global__ __launch_bounds__(256) void conv1_kernel(const float* __restrict__ lbp,
                                                    const float* __restrict__ weff,
                                                    const float* __restrict__ b1,
                                                    __hip_bfloat16* __restrict__ h1) {
  __shared__ float sw[64 * 27];
  __shared__ float sb[64];
  for (int i = threadIdx.x; i < 64 * 27; i += 256) sw[i] = weff[i];
  if (threadIdx.x < 64) sb[threadIdx.x] = b1[threadIdx.x];
  __syncthreads();

  int bf = blockIdx.x;                                   // b*16+f1
  int b = bf >> 4, f1 = bf & 15;
  int pos = blockIdx.y * 256 + threadIdx.x;              // < 12544
  int y1 = pos / W1, x1 = pos - y1 * W1;

  float v[27];
  int k = 0;
#pragma unroll
  for (int kf = 0; kf < 3; ++kf) {
    int fin = f1 - 1 + kf;
    bool fok = (unsigned)fin < (unsigned)NF;
    const float* lf = lbp + ((size_t)b * NF + (fok ? fin : 0)) * HWPIX;
#pragma unroll
    for (int ky = 0; ky < 3; ++ky) {
      int yin = 2 * y1 - 1 + ky;
      bool yok = (unsigned)yin < (unsigned)NH;
#pragma unroll
      for (int kx = 0; kx < 3; ++kx, ++k) {
        int xin = 2 * x1 - 1 + kx;
        bool ok = fok && yok && ((unsigned)xin < (unsigned)NW);
        v[k] = ok ? lf[yin * NW + xin] : 0.0f;
      }
    }
  }

  size_t outbase = (((size_t)bf * H1 + y1) * W1 + x1) * 64;
  for (int oc = 0; oc < 64; ++oc) {
    float acc = sb[oc];
#pragma unroll
    for (int t = 0; t < 27; ++t) acc = fmaf(sw[oc * 27 + t], v[t], acc);
    acc = fmaxf(acc, 0.0f);
    h1[outbase + oc] = __float2bfloat16(acc);
  }
}

// ---------------- conv2 + relu + partial pool ----------------
// block = (b, f2, y2): all 56 x2, all 128 oc2. h1 slab in LDS per ic-chunk.
__global__ __launch_bounds__(256) void conv2_kernel(const __hip_bfloat16* __restrict__ h1,
                                                    const float* __restrict__ w2,
                                                    const float* __restrict__ b2,
                                                    float* __restrict__ partial) {
  __shared__ uint32_t sh32[9 * 113 * (ICC / 2)];         // 65,088 B
  __shared__ float red[256];

  int bid = blockIdx.x;
  int b = bid / 448;
  int r = bid - b * 448;                                 // f2*56 + y2
  int f2 = r / 56;
  int y2 = r - f2 * 56;
  int tid = threadIdx.x;
  int oc2 = tid & 127;
  int xh = tid >> 7;                                     // 0/1 -> x2 halves

  float acc[28];
#pragma unroll
  for (int i = 0; i < 28; ++i) acc[i] = 0.0f;

  for (int ic0 = 0; ic0 < 64; ic0 += ICC) {
    __syncthreads();
    // stage h1[f1=2f2-1..+1][y1=2y2-1..+1][x1=-1..111][ic0..ic0+ICC) into LDS
    for (int idx = tid; idx < 9 * 113 * (ICC / 2); idx += 256) {
      int pos = idx >> 4;                                // dword 16 per pos
      int d = idx & 15;
      int kfky = pos / 113;
      int xi = pos - kfky * 113;
      int kf = kfky / 3, ky = kfky - kf * 3;
      int f1 = 2 * f2 - 1 + kf;
      int y1 = 2 * y2 - 1 + ky;
      int x1 = xi - 1;
      uint32_t val = 0;
      if ((unsigned)f1 < (unsigned)NF && (unsigned)y1 < (unsigned)H1 &&
          (unsigned)x1 < (unsigned)W1) {
        size_t e = ((((size_t)b * NF + f1) * H1 + y1) * W1 + x1) * 64 + ic0;
        val = *reinterpret_cast<const uint32_t*>(
            reinterpret_cast<const char*>(h1) + e * 2 + (size_t)d * 4);
      }
      sh32[idx] = val;
    }
    __syncthreads();

    const float* wbase = w2 + ((size_t)oc2 * 64 + ic0) * 27;
    const __hip_bfloat16* sh = reinterpret_cast<const __hip_bfloat16*>(sh32);
    int xoff = 2 * (xh * 28);
    for (int ic = 0; ic < ICC; ++ic) {
      const __hip_bfloat16* shc = sh + ic;
      const float* wic = wbase + ic * 27;
      int t = 0;
      for (int kf = 0; kf < 3; ++kf) {
        for (int ky = 0; ky < 3; ++ky) {
          int rowbase = (kf * 3 + ky) * 113;
#pragma unroll
          for (int kx = 0; kx < 3; ++kx, ++t) {
            float wv = wic[t];
            const __hip_bfloat16* hp = shc + (size_t)(rowbase + xoff + kx) * ICC;
#pragma unroll
            for (int x2l = 0; x2l < 28; ++x2l) {
              acc[x2l] = fmaf(wv, __bfloat162float(hp[(size_t)x2l * 2 * ICC]), acc[x2l]);
            }
          }
        }
      }
    }
  }

  float bias = b2[oc2];
  float s = 0.0f;
#pragma unroll
  for (int i = 0; i < 28; ++i) s += fmaxf(acc[i] + bias, 0.0f);
  __syncthreads();
  red[tid] = s;
  __syncthreads();
  if (xh == 0) {
    partial[((size_t)b * OC2 + oc2) * 448 + r] = red[tid] + red[tid + 128];
  }
}

__global__ void final_kernel(const float* __restrict__ partial, float* __restrict__ out) {
  int i = blockIdx.x * 256 + threadIdx.x;                // < 512
  float s = 0.0f;
  for (int j = 0; j < 448; ++j) s += partial[(size_t)i * 448 + j];
  out[i] = s / 25088.0f;
}

extern "C" void kernel_launch(void* const* d_in, const int* in_sizes, int n_in,
                              void* d_out, int out_size, void* d_ws, size_t ws_size,
                              hipStream_t stream) {
  const float* x  = (const float*)d_in[0];
  const float* w1 = (const float*)d_in[1];
  const float* b1 = (const float*)d_in[2];
  const float* w2 = (const float*)d_in[3];
  const float* b2 = (const float*)d_in[4];
  float* out = (float*)d_out;

  char* ws = (char*)d_ws;
  // layout (all 256B aligned):
  __hip_bfloat16* h1 = (__hip_bfloat16*)ws;              // 102,760,448 B
  float* gray     = (float*)(ws + 102760448);            // 12,845,056 B
  float* lbp      = (float*)(ws + 115605504);            // 12,845,056 B
  float* weff     = (float*)(ws + 128450560);            // 6,912 B (pad to 6,912+)
  int*   blockmax = (int*)  (ws + 128457472);            // 50,176 B
  int*   framemax = (int*)  (ws + 128507648);            // 256 B
  float* partial  = (float*)(ws + 128507904);            // 917,504 B -> total 129,425,408

  weff_kernel<<<1, 64, 0, stream>>>(w1, weff);
  gray_kernel<<<NPIX / 256, 256, 0, stream>>>(x, gray);
  lbp_kernel<<<dim3(NB * NF, 196), 256, 0, stream>>>(gray, lbp, blockmax);
  framemax_kernel<<<1, 64, 0, stream>>>(blockmax, framemax);
  norm_kernel<<<NPIX / 256, 256, 0, stream>>>(lbp, framemax);
  conv1_kernel<<<dim3(NB * NF, 49), 256, 0, stream>>>(lbp, weff, b1, h1);
  conv2_kernel<<<NB * NF2 * 56, 256, 0, stream>>>(h1, w2, b2, partial);
  final_kernel<<<2, 256, 0, stream>>>(partial, out);
}

// Round 2
// 322.481 us; speedup vs baseline: 4.7320x; 4.7320x over previous
//
#include <hip/hip_runtime.h>
#include <hip/hip_bf16.h>
#include <stdint.h>

// Problem dims
constexpr int NB = 4;          // batch
constexpr int NF = 16;         // frames
constexpr int NH = 224, NW = 224;
constexpr int HWPIX = NH * NW;             // 50176
constexpr int NPIX = NB * NF * HWPIX;      // 3,211,264
constexpr int H1 = 112, W1 = 112;
constexpr int OC2 = 128;

typedef __attribute__((ext_vector_type(8))) __bf16 bf16x8;
typedef __attribute__((ext_vector_type(4))) float f32x4;

#define MFMA16(a, b, c) __builtin_amdgcn_mfma_f32_16x16x32_bf16(a, b, c, 0, 0, 0)

__device__ __forceinline__ void gload_lds16(const void* g, void* l) {
  __builtin_amdgcn_global_load_lds(
      (const __attribute__((address_space(1))) unsigned int*)g,
      (__attribute__((address_space(3))) unsigned int*)l, 16, 0, 0);
}

// ---------------- gray = floor(mean(x, ch) * 255) ----------------
__global__ __launch_bounds__(256) void gray_kernel(const float* __restrict__ x,
                                                   float* __restrict__ gray) {
  int i = blockIdx.x * 256 + threadIdx.x;              // < NPIX
  int b = i / (NF * HWPIX);
  int rem = i - b * (NF * HWPIX);
  const float* xb = x + (size_t)b * 3 * NF * HWPIX + rem;
  float s = xb[0] + xb[NF * HWPIX] + xb[2 * NF * HWPIX];
  gray[i] = floorf((s / 3.0f) * 255.0f);
}

// ---------------- uniform LBP codes + per-block max ----------------
__global__ __launch_bounds__(256) void lbp_kernel(const float* __restrict__ gray,
                                                  float* __restrict__ lbp,
                                                  int* __restrict__ blockmax) {
  int frame = blockIdx.x;                               // 0..63
  int pix = blockIdx.y * 256 + threadIdx.x;             // < 50176
  int y = pix / NW, x = pix - y * NW;
  const float* g = gray + (size_t)frame * HWPIX;

  float n[3][3];
#pragma unroll
  for (int dy = 0; dy < 3; ++dy) {
    int yy = y + dy - 1;
#pragma unroll
    for (int dx = 0; dx < 3; ++dx) {
      int xx = x + dx - 1;
      bool ok = ((unsigned)yy < (unsigned)NH) && ((unsigned)xx < (unsigned)NW);
      n[dy][dx] = ok ? g[yy * NW + xx] : 0.0f;          // cval=0 padding
    }
  }
  float c = n[1][1];

  constexpr double Ad = 0.70711;
  constexpr double Bd = 1.0 - Ad;

  const float s0 = n[1][2];
  const float s2 = n[0][1];
  const float s4 = n[1][0];
  const float s6 = n[2][1];
  const float s1 = (float)(Ad * Bd) * n[0][1] + (float)(Ad * Ad) * n[0][2]
                 + (float)(Bd * Bd) * n[1][1] + (float)(Bd * Ad) * n[1][2];
  const float s3 = (float)(Ad * Ad) * n[0][0] + (float)(Ad * Bd) * n[0][1]
                 + (float)(Bd * Ad) * n[1][0] + (float)(Bd * Bd) * n[1][1];
  const float s5 = (float)(Bd * Ad) * n[1][0] + (float)(Bd * Bd) * n[1][1]
                 + (float)(Ad * Ad) * n[2][0] + (float)(Ad * Bd) * n[2][1];
  const float s7 = (float)(Bd * Bd) * n[1][1] + (float)(Bd * Ad) * n[1][2]
                 + (float)(Ad * Bd) * n[2][1] + (float)(Ad * Ad) * n[2][2];

  bool bb[8] = { s0 >= c, s1 >= c, s2 >= c, s3 >= c,
                 s4 >= c, s5 >= c, s6 >= c, s7 >= c };
  int ones = 0, changes = 0;
#pragma unroll
  for (int p = 0; p < 8; ++p) {
    ones += bb[p] ? 1 : 0;
    changes += (bb[p] != bb[(p + 1) & 7]) ? 1 : 0;
  }
  int code = (changes <= 2) ? ones : 9;
  lbp[(size_t)frame * HWPIX + pix] = (float)code;

  int m = code;
#pragma unroll
  for (int off = 32; off >= 1; off >>= 1) m = max(m, __shfl_down(m, off, 64));
  __shared__ int wm[4];
  if ((threadIdx.x & 63) == 0) wm[threadIdx.x >> 6] = m;
  __syncthreads();
  if (threadIdx.x == 0)
    blockmax[frame * 196 + blockIdx.y] = max(max(wm[0], wm[1]), max(wm[2], wm[3]));
}

__global__ void framemax_kernel(const int* __restrict__ blockmax,
                                int* __restrict__ framemax) {
  int t = threadIdx.x;                                   // 64 threads
  int m = 0;
  for (int j = 0; j < 196; ++j) m = max(m, blockmax[t * 196 + j]);
  framemax[t] = m;
}

__global__ __launch_bounds__(256) void norm_kernel(float* __restrict__ lbp,
                                                   const int* __restrict__ framemax) {
  int i = blockIdx.x * 256 + threadIdx.x;
  int frame = i / HWPIX;
  int m = framemax[frame];
  float v = lbp[i];
  if (m > 0) v = v / (float)m;
  lbp[i] = v;
}

// ---------------- weff[o][k] = sum_c w1[o][c][k] ----------------
__global__ void weff_kernel(const float* __restrict__ w1, float* __restrict__ weff) {
  int o = threadIdx.x;
  if (o < 64) {
    for (int k = 0; k < 27; ++k)
      weff[o * 27 + k] = w1[o * 81 + k] + w1[o * 81 + 27 + k] + w1[o * 81 + 54 + k];
  }
}

// ---------------- w2r[tap][oc][ic] (bf16) from w2[oc][ic][27] ----------------
__global__ __launch_bounds__(256) void w2r_kernel(const float* __restrict__ w2,
                                                  __hip_bfloat16* __restrict__ w2r) {
  int i = blockIdx.x * 256 + threadIdx.x;
  if (i >= 27 * 128 * 64) return;
  int tap = i / (128 * 64);
  int rem = i - tap * (128 * 64);
  int oc = rem >> 6, ic = rem & 63;
  w2r[i] = __float2bfloat16(w2[((size_t)oc * 64 + ic) * 27 + tap]);
}

// ---------------- conv1: lbp -> h1 (bf16, channel-last [b][f][y][x][ic]) -------
__global__ __launch_bounds__(256) void conv1_kernel(const float* __restrict__ lbp,
                                                    const float* __restrict__ weff,
                                                    const float* __restrict__ b1,
                                                    __hip_bfloat16* __restrict__ h1) {
  __shared__ float sw[64 * 27];
  __shared__ float sb[64];
  for (int i = threadIdx.x; i < 64 * 27; i += 256) sw[i] = weff[i];
  if (threadIdx.x < 64) sb[threadIdx.x] = b1[threadIdx.x];
  __syncthreads();

  int bf = blockIdx.x;                                   // b*16+f1
  int b = bf >> 4, f1 = bf & 15;
  int pos = blockIdx.y * 256 + threadIdx.x;              // < 12544
  int y1 = pos / W1, x1 = pos - y1 * W1;

  float v[27];
  int k = 0;
#pragma unroll
  for (int kf = 0; kf < 3; ++kf) {
    int fin = f1 - 1 + kf;
    bool fok = (unsigned)fin < (unsigned)NF;
    const float* lf = lbp + ((size_t)b * NF + (fok ? fin : 0)) * HWPIX;
#pragma unroll
    for (int ky = 0; ky < 3; ++ky) {
      int yin = 2 * y1 - 1 + ky;
      bool yok = (unsigned)yin < (unsigned)NH;
#pragma unroll
      for (int kx = 0; kx < 3; ++kx, ++k) {
        int xin = 2 * x1 - 1 + kx;
        bool ok = fok && yok && ((unsigned)xin < (unsigned)NW);
        v[k] = ok ? lf[yin * NW + xin] : 0.0f;
      }
    }
  }

  size_t outbase = (((size_t)bf * H1 + y1) * W1 + x1) * 64;
  for (int oc = 0; oc < 64; ++oc) {
    float acc = sb[oc];
#pragma unroll
    for (int t = 0; t < 27; ++t) acc = fmaf(sw[oc * 27 + t], v[t], acc);
    acc = fmaxf(acc, 0.0f);
    h1[outbase + oc] = __float2bfloat16(acc);
  }
}

// ---------------- conv2 as implicit-GEMM MFMA + fused bias/relu/pool ----------
// block = (g = y2-pair, f2, b); tile 128 oc x 112 pos; 4 waves x (32 oc x 112 pos).
// h1 slab per kf in LDS: [5 y1-rows][113 xs][64 ic] bf16 with xs-keyed granule
// XOR swizzle (applied on the *global source* of global_load_lds; LDS dest linear).
constexpr int SLAB_ROW = 113 * 128;   // bytes per y1-row (14,464)

__global__ __launch_bounds__(256, 2) void conv2_mfma(
    const __hip_bfloat16* __restrict__ h1,
    const __hip_bfloat16* __restrict__ w2r,
    const float* __restrict__ b2,
    float* __restrict__ partial) {
  __shared__ __align__(16) char slab[5 * SLAB_ROW];      // 72,320 B

  const int g = blockIdx.x;                              // 0..27 (y2 pair)
  const int f2 = blockIdx.y;                             // 0..7
  const int b = blockIdx.z;                              // 0..3
  const int tid = threadIdx.x;
  const int lane = tid & 63, wid = tid >> 6;
  const int c = lane & 15, q = lane >> 4;
  const int oc0 = wid * 32;

  // zero the xs=0 pad column once (never written by staging)
  if (tid < 40) {
    int r = tid >> 3, s = tid & 7;
    *(int4*)(slab + r * SLAB_ROW + s * 16) = make_int4(0, 0, 0, 0);
  }

  // per-lane, per-j precomputed position decode
  int x2v[7], rbase[7];
#pragma unroll
  for (int j = 0; j < 7; ++j) {
    int pos = j * 16 + c;
    int yo = pos >= 56 ? 1 : 0;
    x2v[j] = pos - 56 * yo;
    rbase[j] = yo * 2 * SLAB_ROW + x2v[j] * 256;
  }

  float bias[2][4];
#pragma unroll
  for (int i = 0; i < 2; ++i)
#pragma unroll
    for (int r = 0; r < 4; ++r) bias[i][r] = b2[oc0 + i * 16 + q * 4 + r];

  f32x4 acc[2][7];
#pragma unroll
  for (int i = 0; i < 2; ++i)
#pragma unroll
    for (int j = 0; j < 7; ++j) acc[i][j] = f32x4{0.f, 0.f, 0.f, 0.f};

  const char* h1b = (const char*)h1;
  const __bf16* w2rb = (const __bf16*)w2r;

  for (int kf = 0; kf < 3; ++kf) {
    __syncthreads();
    // ---- stage slab: rows r=0..4 (y1 = 4g-1+r), xs 1..112 interior ----
    const int f1 = 2 * f2 - 1 + kf;
    const bool fok = (unsigned)f1 < (unsigned)NF;
    for (int t = wid; t < 70; t += 4) {
      int r = t / 14, ck = t - r * 14;
      int y1 = 4 * g - 1 + r;
      int xs0 = 1 + ck * 8;
      char* ldst = slab + r * SLAB_ROW + xs0 * 128;      // wave-uniform
      if (fok && (unsigned)y1 < (unsigned)H1) {
        int xs = xs0 + (lane >> 3);
        int slot = lane & 7;
        int K = (xs >> 1) & 7;
        int x1 = xs - 1;
        const char* gsrc = h1b +
            ((((size_t)(b * NF + f1) * H1 + y1) * W1 + x1) << 7) + ((slot ^ K) << 4);
        gload_lds16(gsrc, ldst);
      } else {
        *(int4*)(ldst + lane * 16) = make_int4(0, 0, 0, 0);
      }
    }
    __syncthreads();

    // ---- 18 k-steps: (ky,kx) taps x 2 ic-halves ----
#pragma unroll
    for (int ky = 0; ky < 3; ++ky) {
#pragma unroll
      for (int kx = 0; kx < 3; ++kx) {
        const int tap = kf * 9 + ky * 3 + kx;
        const __bf16* wtap = w2rb + ((size_t)(tap * 128 + oc0 + c) << 6) + q * 8;
        const int sx = kx >> 1;                          // floor(kx/2)
        const int imm = ky * SLAB_ROW + kx * 128;
#pragma unroll
        for (int ich = 0; ich < 2; ++ich) {
          bf16x8 a0 = *(const bf16x8*)(wtap + ich * 32);
          bf16x8 a1 = *(const bf16x8*)(wtap + 16 * 64 + ich * 32);
#pragma unroll
          for (int j = 0; j < 7; ++j) {
            int K = (x2v[j] + sx) & 7;
            int slot = (ich * 4 + q) ^ K;
            bf16x8 bv = *(const bf16x8*)(slab + rbase[j] + imm + slot * 16);
            acc[0][j] = MFMA16(a0, bv, acc[0][j]);
            acc[1][j] = MFMA16(a1, bv, acc[1][j]);
          }
        }
      }
    }
  }

  // ---- epilogue: bias + relu + pool over 112 positions, reduce 16 lanes ----
#pragma unroll
  for (int i = 0; i < 2; ++i) {
#pragma unroll
    for (int r = 0; r < 4; ++r) {
      float s = 0.0f;
#pragma unroll
      for (int j = 0; j < 7; ++j) s += fmaxf(acc[i][j][r] + bias[i][r], 0.0f);
      s += __shfl_xor(s, 1);
      s += __shfl_xor(s, 2);
      s += __shfl_xor(s, 4);
      s += __shfl_xor(s, 8);
      if (c == 0) {
        int oc = oc0 + i * 16 + q * 4 + r;
        partial[((size_t)b * OC2 + oc) * 224 + f2 * 28 + g] = s;
      }
    }
  }
}

__global__ void final_kernel(const float* __restrict__ partial, float* __restrict__ out) {
  int i = blockIdx.x * 256 + threadIdx.x;                // < 512
  float s = 0.0f;
  for (int j = 0; j < 224; ++j) s += partial[(size_t)i * 224 + j];
  out[i] = s / 25088.0f;
}

extern "C" void kernel_launch(void* const* d_in, const int* in_sizes, int n_in,
                              void* d_out, int out_size, void* d_ws, size_t ws_size,
                              hipStream_t stream) {
  const float* x  = (const float*)d_in[0];
  const float* w1 = (const float*)d_in[1];
  const float* b1 = (const float*)d_in[2];
  const float* w2 = (const float*)d_in[3];
  const float* b2 = (const float*)d_in[4];
  float* out = (float*)d_out;

  char* ws = (char*)d_ws;
  __hip_bfloat16* h1 = (__hip_bfloat16*)ws;              // 102,760,448 B
  float* gray     = (float*)(ws + 102760448);            // 12,845,056 B
  float* lbp      = (float*)(ws + 115605504);            // 12,845,056 B
  float* weff     = (float*)(ws + 128450560);            // 6,912 B
  int*   blockmax = (int*)  (ws + 128457472);            // 50,176 B
  int*   framemax = (int*)  (ws + 128507648);            // 256 B
  float* partial  = (float*)(ws + 128507904);            // 458,752 B
  __hip_bfloat16* w2r = (__hip_bfloat16*)(ws + 128966656); // 442,368 B -> 129,409,024

  weff_kernel<<<1, 64, 0, stream>>>(w1, weff);
  w2r_kernel<<<(27 * 128 * 64 + 255) / 256, 256, 0, stream>>>(w2, w2r);
  gray_kernel<<<NPIX / 256, 256, 0, stream>>>(x, gray);
  lbp_kernel<<<dim3(NB * NF, 196), 256, 0, stream>>>(gray, lbp, blockmax);
  framemax_kernel<<<1, 64, 0, stream>>>(blockmax, framemax);
  norm_kernel<<<NPIX / 256, 256, 0, stream>>>(lbp, framemax);
  conv1_kernel<<<dim3(NB * NF, 49), 256, 0, stream>>>(lbp, weff, b1, h1);
  conv2_mfma<<<dim3(28, 8, 4), 256, 0, stream>>>(h1, w2r, b2, partial);
  final_kernel<<<2, 256, 0, stream>>>(partial, out);
}

// Round 4
// 172.751 us; speedup vs baseline: 8.8334x; 1.8667x over previous
//
#include <hip/hip_runtime.h>
#include <hip/hip_bf16.h>
#include <stdint.h>

// Problem dims
constexpr int NB = 4;          // batch
constexpr int NF = 16;         // frames
constexpr int NH = 224, NW = 224;
constexpr int HWPIX = NH * NW;             // 50176
constexpr int H1 = 112, W1 = 112;
constexpr int OC2 = 128;

typedef __attribute__((ext_vector_type(8))) __bf16 bf16x8;
typedef __attribute__((ext_vector_type(4))) float f32x4;

#define MFMA16(a, b, c) __builtin_amdgcn_mfma_f32_16x16x32_bf16(a, b, c, 0, 0, 0)

__device__ __forceinline__ void gload_lds16(const void* g, void* l) {
  __builtin_amdgcn_global_load_lds(
      (const __attribute__((address_space(1))) unsigned int*)g,
      (__attribute__((address_space(3))) unsigned int*)l, 16, 0, 0);
}

__device__ __forceinline__ ushort bf16u(float f) {
  __hip_bfloat16 h = __float2bfloat16(f);
  return *(ushort*)&h;
}

// ---------------- fused gray + uniform LBP codes (u8) + per-tile max ----------
__global__ __launch_bounds__(256) void graylbp_kernel(const float* __restrict__ x,
                                                      unsigned char* __restrict__ lbpc,
                                                      int* __restrict__ blockmax) {
  __shared__ float sg[18 * 18];
  const int tile = blockIdx.x;                          // 0..195
  const int frame = blockIdx.y;                         // 0..63
  const int ty = tile / 14, tx = tile - ty * 14;
  const int b = frame >> 4, f = frame & 15;
  const float* xb = x + ((size_t)b * 3 * NF + f) * HWPIX;   // channel stride NF*HWPIX

  for (int e = threadIdx.x; e < 324; e += 256) {
    int r = e / 18, cc = e - 18 * r;
    int y = ty * 16 + r - 1, xx = tx * 16 + cc - 1;
    float v = 0.0f;
    if ((unsigned)y < (unsigned)NH && (unsigned)xx < (unsigned)NW) {
      size_t o = (size_t)y * NW + xx;
      float s = xb[o] + xb[o + (size_t)NF * HWPIX] + xb[o + 2 * (size_t)NF * HWPIX];
      v = floorf((s / 3.0f) * 255.0f);
    }
    sg[e] = v;
  }
  __syncthreads();

  const int r = threadIdx.x >> 4, cc = threadIdx.x & 15;
  float n[3][3];
#pragma unroll
  for (int dy = 0; dy < 3; ++dy)
#pragma unroll
    for (int dx = 0; dx < 3; ++dx) n[dy][dx] = sg[(r + dy) * 18 + (cc + dx)];
  float c = n[1][1];

  constexpr double Ad = 0.70711;
  constexpr double Bd = 1.0 - Ad;

  const float s0 = n[1][2];
  const float s2 = n[0][1];
  const float s4 = n[1][0];
  const float s6 = n[2][1];
  const float s1 = (float)(Ad * Bd) * n[0][1] + (float)(Ad * Ad) * n[0][2]
                 + (float)(Bd * Bd) * n[1][1] + (float)(Bd * Ad) * n[1][2];
  const float s3 = (float)(Ad * Ad) * n[0][0] + (float)(Ad * Bd) * n[0][1]
                 + (float)(Bd * Ad) * n[1][0] + (float)(Bd * Bd) * n[1][1];
  const float s5 = (float)(Bd * Ad) * n[1][0] + (float)(Bd * Bd) * n[1][1]
                 + (float)(Ad * Ad) * n[2][0] + (float)(Ad * Bd) * n[2][1];
  const float s7 = (float)(Bd * Bd) * n[1][1] + (float)(Bd * Ad) * n[1][2]
                 + (float)(Ad * Bd) * n[2][1] + (float)(Ad * Ad) * n[2][2];

  bool bb[8] = { s0 >= c, s1 >= c, s2 >= c, s3 >= c,
                 s4 >= c, s5 >= c, s6 >= c, s7 >= c };
  int ones = 0, changes = 0;
#pragma unroll
  for (int p = 0; p < 8; ++p) {
    ones += bb[p] ? 1 : 0;
    changes += (bb[p] != bb[(p + 1) & 7]) ? 1 : 0;
  }
  int code = (changes <= 2) ? ones : 9;
  lbpc[(size_t)frame * HWPIX + (ty * 16 + r) * NW + tx * 16 + cc] = (unsigned char)code;

  int m = code;
#pragma unroll
  for (int off = 32; off >= 1; off >>= 1) m = max(m, __shfl_down(m, off, 64));
  __shared__ int wm[4];
  if ((threadIdx.x & 63) == 0) wm[threadIdx.x >> 6] = m;
  __syncthreads();
  if (threadIdx.x == 0)
    blockmax[frame * 196 + tile] = max(max(wm[0], wm[1]), max(wm[2], wm[3]));
}

// ---------------- per-frame max + normalization LUT (bf16) ----------------
__global__ void framemax_tab_kernel(const int* __restrict__ blockmax,
                                    __hip_bfloat16* __restrict__ normtab) {
  int t = threadIdx.x;                                   // 256
  int f = t >> 2, part = t & 3;
  int m = 0;
  for (int j = part; j < 196; j += 4) m = max(m, blockmax[f * 196 + j]);
  m = max(m, __shfl_xor(m, 1, 64));
  m = max(m, __shfl_xor(m, 2, 64));
  if (part == 0) {
    for (int cde = 0; cde < 16; ++cde) {
      float v = (m > 0) ? ((float)cde / (float)m) : (float)cde;  // exact f32 div like ref
      normtab[f * 16 + cde] = __float2bfloat16(v);
    }
  }
}

// ---------------- w1r[oc][32] bf16: 27 summed-channel taps + bias@27 + pad ----
__global__ void w1r_kernel(const float* __restrict__ w1, const float* __restrict__ b1,
                           __hip_bfloat16* __restrict__ w1r) {
  int o = threadIdx.x;
  if (o >= 64) return;
  for (int k = 0; k < 32; ++k) {
    float v;
    if (k < 27)      v = w1[o * 81 + k] + w1[o * 81 + 27 + k] + w1[o * 81 + 54 + k];
    else if (k == 27) v = b1[o];
    else              v = 0.0f;
    w1r[o * 32 + k] = __float2bfloat16(v);
  }
}

// ---------------- w2r[tap][oc][ic] (bf16) from w2[oc][ic][27] ----------------
__global__ __launch_bounds__(256) void w2r_kernel(const float* __restrict__ w2,
                                                  __hip_bfloat16* __restrict__ w2r) {
  int i = blockIdx.x * 256 + threadIdx.x;
  if (i >= 27 * 128 * 64) return;
  int tap = i / (128 * 64);
  int rem = i - tap * (128 * 64);
  int oc = rem >> 6, ic = rem & 63;
  w2r[i] = __float2bfloat16(w2[((size_t)oc * 64 + ic) * 27 + tap]);
}

// ---------------- conv1 as MFMA implicit GEMM --------------------------------
// block = (g: 4 y1-rows, bf). Tile: 64 oc x 448 pos. K=32 (27 taps + bias + pad).
// lbp staged as bf16 (LUT-normalized) in LDS; epilogue via swizzled LDS buffer
// so h1 stores are fully coalesced b128.
__global__ __launch_bounds__(256, 2) void conv1_mfma(
    const unsigned char* __restrict__ lbpc,
    const __hip_bfloat16* __restrict__ normtab,
    const __hip_bfloat16* __restrict__ w1r,
    __hip_bfloat16* __restrict__ h1) {
  __shared__ ushort stab[48];
  __shared__ __align__(16) ushort tile[3 * 9 * 240];     // 12,960 B
  __shared__ __align__(16) ushort epi[448 * 64];         // 57,344 B

  const int g = blockIdx.x;                              // 0..27 (y1 = 4g..4g+3)
  const int bf = blockIdx.y;                             // 0..63
  const int b = bf >> 4, f1 = bf & 15;
  const int tid = threadIdx.x;
  const int lane = tid & 63, w = tid >> 6;               // wave w owns y1-row 4g+w
  const int c = lane & 15, q = lane >> 4;

  if (tid < 48) {
    int kf = tid >> 4;
    int fin = f1 - 1 + kf;
    stab[tid] = ((unsigned)fin < (unsigned)NF)
        ? ((const ushort*)normtab)[(b * NF + fin) * 16 + (tid & 15)] : (ushort)0;
  }
  __syncthreads();

  // stage lbp tile: [kf 0..2][row 0..8 (y_in = 8g-1+row)][xx 0..239 (x_in = xx-1)]
  for (int idx = tid; idx < 3 * 9 * 240; idx += 256) {
    int kf = idx / 2160;
    int rem = idx - kf * 2160;
    int row = rem / 240;
    int xx = rem - row * 240;
    int fin = f1 - 1 + kf;
    int yin = 8 * g - 1 + row;
    int xin = xx - 1;
    ushort v = 0;
    if ((unsigned)fin < (unsigned)NF && (unsigned)yin < (unsigned)NH &&
        (unsigned)xin < (unsigned)NW) {
      int code = lbpc[((size_t)(b * NF + fin)) * HWPIX + yin * NW + xin];
      v = stab[kf * 16 + code];
    }
    tile[idx] = v;
  }

  // A fragments: lane holds w1r[oc = ocg*16 + c][k = q*8 .. q*8+7]
  bf16x8 afr[4];
  const __bf16* w1rb = (const __bf16*)w1r;
#pragma unroll
  for (int ocg = 0; ocg < 4; ++ocg)
    afr[ocg] = *(const bf16x8*)(w1rb + ((ocg * 16 + c) << 5) + q * 8);

  // per-lane gather precompute: k = q*8+j -> (kf,ky,kx) tile offset
  int pre[8]; ushort fb[8]; bool vld[8];
#pragma unroll
  for (int j = 0; j < 8; ++j) {
    int k = q * 8 + j;
    vld[j] = (k < 27);
    fb[j] = (k == 27) ? (ushort)0x3F80 : (ushort)0;      // bias lane: input 1.0
    int kf = k / 9, r9 = k - 9 * kf;
    int ky = r9 / 3, kx = r9 - 3 * ky;
    pre[j] = kf * 2160 + (2 * w + ky) * 240 + kx + 2 * c;
  }

  __syncthreads();

  const f32x4 zero4 = {0.f, 0.f, 0.f, 0.f};
  for (int fx = 0; fx < 7; ++fx) {
    union { bf16x8 v; ushort u[8]; } bu;
#pragma unroll
    for (int j = 0; j < 8; ++j)
      bu.u[j] = vld[j] ? tile[pre[j] + 32 * fx] : fb[j];

    const int posl = w * 112 + fx * 16 + c;
    const int swz = (posl & 7) << 4;
    const int ebase = posl * 128 + q * 8;
#pragma unroll
    for (int ocg = 0; ocg < 4; ++ocg) {
      f32x4 acc = MFMA16(afr[ocg], bu.v, zero4);
      ushort4 o;
      o.x = bf16u(fmaxf(acc[0], 0.0f));
      o.y = bf16u(fmaxf(acc[1], 0.0f));
      o.z = bf16u(fmaxf(acc[2], 0.0f));
      o.w = bf16u(fmaxf(acc[3], 0.0f));
      *(ushort4*)((char*)epi + ((ebase + ocg * 32) ^ swz)) = o;
    }
  }
  __syncthreads();

  // coalesced store: block output is one contiguous 57,344 B span of h1
  const size_t blockbase = ((size_t)(bf * H1 + 4 * g) * W1) * 128;
  char* h1b = (char*)h1;
  const char* epb = (const char*)epi;
  for (int m = tid; m < 3584; m += 256) {
    int byte = m * 16;
    int posl = m >> 3;
    int src = byte ^ ((posl & 7) << 4);
    *(int4*)(h1b + blockbase + byte) = *(const int4*)(epb + src);
  }
}

// ---------------- conv2 as implicit-GEMM MFMA + fused bias/relu/pool ----------
constexpr int SLAB_ROW = 113 * 128;   // bytes per y1-row (14,464)

__global__ __launch_bounds__(256, 2) void conv2_mfma(
    const __hip_bfloat16* __restrict__ h1,
    const __hip_bfloat16* __restrict__ w2r,
    const float* __restrict__ b2,
    float* __restrict__ partial) {
  __shared__ __align__(16) char slab[5 * SLAB_ROW];      // 72,320 B

  const int g = blockIdx.x;                              // 0..27 (y2 pair)
  const int f2 = blockIdx.y;                             // 0..7
  const int b = blockIdx.z;                              // 0..3
  const int tid = threadIdx.x;
  const int lane = tid & 63, wid = tid >> 6;
  const int c = lane & 15, q = lane >> 4;
  const int oc0 = wid * 32;

  if (tid < 40) {
    int r = tid >> 3, s = tid & 7;
    *(int4*)(slab + r * SLAB_ROW + s * 16) = make_int4(0, 0, 0, 0);
  }

  int x2v[7], rbase[7];
#pragma unroll
  for (int j = 0; j < 7; ++j) {
    int pos = j * 16 + c;
    int yo = pos >= 56 ? 1 : 0;
    x2v[j] = pos - 56 * yo;
    rbase[j] = yo * 2 * SLAB_ROW + x2v[j] * 256;
  }

  float bias[2][4];
#pragma unroll
  for (int i = 0; i < 2; ++i)
#pragma unroll
    for (int r = 0; r < 4; ++r) bias[i][r] = b2[oc0 + i * 16 + q * 4 + r];

  f32x4 acc[2][7];
#pragma unroll
  for (int i = 0; i < 2; ++i)
#pragma unroll
    for (int j = 0; j < 7; ++j) acc[i][j] = f32x4{0.f, 0.f, 0.f, 0.f};

  const char* h1b = (const char*)h1;
  const __bf16* w2rb = (const __bf16*)w2r;

  for (int kf = 0; kf < 3; ++kf) {
    __syncthreads();
    const int f1 = 2 * f2 - 1 + kf;
    const bool fok = (unsigned)f1 < (unsigned)NF;
    for (int t = wid; t < 70; t += 4) {
      int r = t / 14, ck = t - r * 14;
      int y1 = 4 * g - 1 + r;
      int xs0 = 1 + ck * 8;
      char* ldst = slab + r * SLAB_ROW + xs0 * 128;      // wave-uniform
      if (fok && (unsigned)y1 < (unsigned)H1) {
        int xs = xs0 + (lane >> 3);
        int slot = lane & 7;
        int K = (xs >> 1) & 7;
        int x1 = xs - 1;
        const char* gsrc = h1b +
            ((((size_t)(b * NF + f1) * H1 + y1) * W1 + x1) << 7) + ((slot ^ K) << 4);
        gload_lds16(gsrc, ldst);
      } else {
        *(int4*)(ldst + lane * 16) = make_int4(0, 0, 0, 0);
      }
    }
    __syncthreads();

#pragma unroll
    for (int ky = 0; ky < 3; ++ky) {
#pragma unroll
      for (int kx = 0; kx < 3; ++kx) {
        const int tap = kf * 9 + ky * 3 + kx;
        const __bf16* wtap = w2rb + ((size_t)(tap * 128 + oc0 + c) << 6) + q * 8;
        const int sx = kx >> 1;
        const int imm = ky * SLAB_ROW + kx * 128;
#pragma unroll
        for (int ich = 0; ich < 2; ++ich) {
          bf16x8 a0 = *(const bf16x8*)(wtap + ich * 32);
          bf16x8 a1 = *(const bf16x8*)(wtap + 16 * 64 + ich * 32);
#pragma unroll
          for (int j = 0; j < 7; ++j) {
            int K = (x2v[j] + sx) & 7;
            int slot = (ich * 4 + q) ^ K;
            bf16x8 bv = *(const bf16x8*)(slab + rbase[j] + imm + slot * 16);
            acc[0][j] = MFMA16(a0, bv, acc[0][j]);
            acc[1][j] = MFMA16(a1, bv, acc[1][j]);
          }
        }
      }
    }
  }

#pragma unroll
  for (int i = 0; i < 2; ++i) {
#pragma unroll
    for (int r = 0; r < 4; ++r) {
      float s = 0.0f;
#pragma unroll
      for (int j = 0; j < 7; ++j) s += fmaxf(acc[i][j][r] + bias[i][r], 0.0f);
      s += __shfl_xor(s, 1);
      s += __shfl_xor(s, 2);
      s += __shfl_xor(s, 4);
      s += __shfl_xor(s, 8);
      if (c == 0) {
        int oc = oc0 + i * 16 + q * 4 + r;
        partial[((size_t)b * OC2 + oc) * 224 + f2 * 28 + g] = s;
      }
    }
  }
}

__global__ void final_kernel(const float* __restrict__ partial, float* __restrict__ out) {
  int i = blockIdx.x * 256 + threadIdx.x;                // < 512
  float s = 0.0f;
  for (int j = 0; j < 224; ++j) s += partial[(size_t)i * 224 + j];
  out[i] = s / 25088.0f;
}

extern "C" void kernel_launch(void* const* d_in, const int* in_sizes, int n_in,
                              void* d_out, int out_size, void* d_ws, size_t ws_size,
                              hipStream_t stream) {
  const float* x  = (const float*)d_in[0];
  const float* w1 = (const float*)d_in[1];
  const float* b1 = (const float*)d_in[2];
  const float* w2 = (const float*)d_in[3];
  const float* b2 = (const float*)d_in[4];
  float* out = (float*)d_out;

  char* ws = (char*)d_ws;
  __hip_bfloat16* h1 = (__hip_bfloat16*)ws;                    // 102,760,448 B
  unsigned char* lbpc = (unsigned char*)(ws + 102760448);      // 3,211,264 B
  int* blockmax = (int*)(ws + 105971712);                      // 50,176 B
  __hip_bfloat16* normtab = (__hip_bfloat16*)(ws + 106021888); // 2,048 B
  float* partial = (float*)(ws + 106023936);                   // 458,752 B
  __hip_bfloat16* w2r = (__hip_bfloat16*)(ws + 106482688);     // 442,368 B
  __hip_bfloat16* w1r = (__hip_bfloat16*)(ws + 106925056);     // 4,096 B -> 106,929,152

  w1r_kernel<<<1, 64, 0, stream>>>(w1, b1, w1r);
  w2r_kernel<<<(27 * 128 * 64 + 255) / 256, 256, 0, stream>>>(w2, w2r);
  graylbp_kernel<<<dim3(196, NB * NF), 256, 0, stream>>>(x, lbpc, blockmax);
  framemax_tab_kernel<<<1, 256, 0, stream>>>(blockmax, normtab);
  conv1_mfma<<<dim3(28, NB * NF), 256, 0, stream>>>(lbpc, normtab, w1r, h1);
  conv2_mfma<<<dim3(28, 8, 4), 256, 0, stream>>>(h1, w2r, b2, partial);
  final_kernel<<<2, 256, 0, stream>>>(partial, out);
}